// Round 1
// baseline (119.996 us; speedup 1.0000x reference)
//
#include <hip/hip_runtime.h>

#define B_ 64
#define K_ 16
#define N_ 65536
#define CHUNKS 8
#define NPAIR 120            // pairs (k,l) with k<l
#define NVAL 136             // 120 pair sums + 16 rowsums
#define EPS_ 1e-8f
#define SMOOTH_ 0.1f

// ---- DPP wave-64 sum: result lands in lane 63 (VALU pipe, no LDS) ----
template <int CTRL>
__device__ __forceinline__ float dpp_add_step(float x) {
    int y = __builtin_amdgcn_update_dpp(0, __float_as_int(x), CTRL, 0xf, 0xf, true);
    return x + __int_as_float(y);
}

__device__ __forceinline__ float wave_sum_lane63(float x) {
    x = dpp_add_step<0x111>(x); // row_shr:1
    x = dpp_add_step<0x112>(x); // row_shr:2
    x = dpp_add_step<0x114>(x); // row_shr:4
    x = dpp_add_step<0x118>(x); // row_shr:8  -> lane 15 of each row16 = row sum
    x = dpp_add_step<0x142>(x); // row_bcast:15
    x = dpp_add_step<0x143>(x); // row_bcast:31 -> lane 63 = full wave sum
    return x;
}

__global__ void zero_ws(float* __restrict__ ws) {
    int i = blockIdx.x * 256 + threadIdx.x;
    if (i < B_ * NVAL) ws[i] = 0.f;
}

// One streaming pass: per (b, chunk) block accumulate raw pair products and rowsums.
__global__ __launch_bounds__(256, 2)
void dice_accum(const float* __restrict__ am, float* __restrict__ ws) {
    const int b     = blockIdx.x >> 3;            // CHUNKS == 8
    const int chunk = blockIdx.x & (CHUNKS - 1);
    const int tid   = threadIdx.x;

    float g[NPAIR];
    float rs[K_];
#pragma unroll
    for (int p = 0; p < NPAIR; ++p) g[p] = 0.f;
#pragma unroll
    for (int k = 0; k < K_; ++k) rs[k] = 0.f;

    const float4* __restrict__ base =
        reinterpret_cast<const float4*>(am) + (size_t)b * K_ * (N_ / 4);
    int idx = chunk * (N_ / CHUNKS / 4) + tid;    // float4 index within a row

    for (int it = 0; it < (N_ / CHUNKS) / (4 * 256); ++it) {  // 8 iterations
        float4 v[K_];
#pragma unroll
        for (int k = 0; k < K_; ++k) v[k] = base[k * (N_ / 4) + idx];
#pragma unroll
        for (int k = 0; k < K_; ++k)
            rs[k] += (v[k].x + v[k].y) + (v[k].z + v[k].w);
#pragma unroll
        for (int k = 0; k < K_; ++k) {
#pragma unroll
            for (int l = k + 1; l < K_; ++l) {
                const int p = k * (K_ - 1) - (k * (k - 1)) / 2 + (l - k - 1); // constexpr per unroll
                g[p] += v[k].x * v[l].x + v[k].y * v[l].y
                      + v[k].z * v[l].z + v[k].w * v[l].w;
            }
        }
        idx += 256;
    }

    // Per-wave reduce each of the 136 values on the VALU pipe; lane 63 commits.
    const int lane = tid & 63;
    float* __restrict__ wsb = ws + b * NVAL;
#pragma unroll
    for (int p = 0; p < NPAIR; ++p) {
        float s = wave_sum_lane63(g[p]);
        if (lane == 63) atomicAdd(&wsb[p], s);
    }
#pragma unroll
    for (int k = 0; k < K_; ++k) {
        float s = wave_sum_lane63(rs[k]);
        if (lane == 63) atomicAdd(&wsb[NPAIR + k], s);
    }
}

// Deferred normalization + dice + mean over (b, pairs). Tiny.
__global__ void dice_finalize(const float* __restrict__ ws, float* __restrict__ out) {
    const int tid = threadIdx.x;
    __shared__ float red[128];
    float acc = 0.f;
    if (tid < NPAIR) {
        int rem = tid, k = 0;
        while (rem >= K_ - 1 - k) { rem -= K_ - 1 - k; ++k; }
        const int l = k + 1 + rem;
        for (int b = 0; b < B_; ++b) {
            const float* wsb = ws + b * NVAL;
            float rsk  = wsb[NPAIR + k];
            float rsl  = wsb[NPAIR + l];
            float graw = wsb[tid];
            float dk = rsk + EPS_, dl = rsl + EPS_;
            float gram = graw / (dk * dl);          // gram of normalized an
            float u    = rsk / dk + rsl / dl;       // sums_k + sums_l
            acc += (2.f * gram + SMOOTH_) / (u + SMOOTH_);
        }
    }
    red[tid] = acc;
    __syncthreads();
    if (tid == 0) {
        float t = 0.f;
        for (int i = 0; i < 128; ++i) t += red[i];
        out[0] = t / (float)(B_ * NPAIR);
    }
}

extern "C" void kernel_launch(void* const* d_in, const int* in_sizes, int n_in,
                              void* d_out, int out_size, void* d_ws, size_t ws_size,
                              hipStream_t stream) {
    const float* am = (const float*)d_in[0];
    float* ws  = (float*)d_ws;
    float* out = (float*)d_out;

    hipLaunchKernelGGL(zero_ws, dim3((B_ * NVAL + 255) / 256), dim3(256), 0, stream, ws);
    hipLaunchKernelGGL(dice_accum, dim3(B_ * CHUNKS), dim3(256), 0, stream, am, ws);
    hipLaunchKernelGGL(dice_finalize, dim3(1), dim3(128), 0, stream, ws, out);
}